// Round 2
// baseline (192.908 us; speedup 1.0000x reference)
//
#include <hip/hip_runtime.h>
#include <math.h>

__device__ __forceinline__ float dot4(float4 a, float4 b){
    return a.x*b.x + a.y*b.y + a.z*b.z + a.w*b.w;
}

// Reduce four per-lane values across the 64-lane wave simultaneously.
// Result: lanes with (lane&3)==j hold sum of aj. 7 shuffles total.
__device__ __forceinline__ float reduce4(float a0, float a1, float a2, float a3, int lane){
    int b0 = lane & 1, b1 = lane & 2;
    float r  = b0 ? a1 : a0;
    float rt = b0 ? a0 : a1;
    r += __shfl_xor(rt, 1);
    float s  = b0 ? a3 : a2;
    float st = b0 ? a2 : a3;
    s += __shfl_xor(st, 1);
    float u  = b1 ? s : r;
    float ut = b1 ? r : s;
    u += __shfl_xor(ut, 2);
    u += __shfl_xor(u, 4);
    u += __shfl_xor(u, 8);
    u += __shfl_xor(u, 16);
    u += __shfl_xor(u, 32);
    return u;   // lane&3 selects which sum
}

// ---------------------------------------------------------------------------
// K1: AvgPool3d 16^3 : x (64,128,128,128) f32 -> seq (64*512)
// One wave per (c,od,oh); 1KB coalesced per 64-lane float4 load.
// ---------------------------------------------------------------------------
__global__ __launch_bounds__(256) void pool_k(const float* __restrict__ x,
                                              float* __restrict__ seq){
    int tid  = threadIdx.x;
    int lane = tid & 63;
    int wid  = blockIdx.x * 4 + (tid >> 6);   // 0..4095
    int c  = wid >> 6;
    int od = (wid >> 3) & 7;
    int oh = wid & 7;
    int half = lane >> 5;
    int f    = lane & 31;

    const float4* px = (const float4*)x;
    size_t base = ((size_t)(c * 128 + od * 16) * 128 + (size_t)(oh * 16 + half)) * 32 + f;

    float acc = 0.f;
    for (int i = 0; i < 16; i++){
        size_t o = base + (size_t)i * 4096;
        #pragma unroll
        for (int jj = 0; jj < 8; jj++){
            float4 v = px[o + (size_t)jj * 64];
            acc += (v.x + v.y) + (v.z + v.w);
        }
    }
    acc += __shfl_xor(acc, 1);
    acc += __shfl_xor(acc, 2);
    acc += __shfl_xor(acc, 32);
    if (lane < 32 && (lane & 3) == 0){
        int ow = lane >> 2;
        seq[c * 512 + od * 64 + oh * 8 + ow] = acc * (1.0f / 4096.0f);
    }
}

// ---------------------------------------------------------------------------
// K2: in_proj  xz[l,e] = dot(seq[l,:512], Win[e,:512])   (64 x 2048)
// Wave computes a 4l x 16e tile: seq rows in regs, W row loaded once per e.
// 512 blocks x 256 threads = 2048 waves.
// ---------------------------------------------------------------------------
__global__ __launch_bounds__(256) void inproj_k(const float* __restrict__ seq,
                                                const float* __restrict__ Win,
                                                float* __restrict__ xz){
    int lane = threadIdx.x & 63;
    int wid  = blockIdx.x * 4 + (threadIdx.x >> 6);  // 0..2047
    int l0 = (wid >> 7) << 2;        // 0,4,...,60
    int e0 = (wid & 127) << 4;       // 0,16,...,2032
    const float4* S = (const float4*)seq;
    float4 s0a = S[(size_t)(l0+0)*128 + lane], s0b = S[(size_t)(l0+0)*128 + lane + 64];
    float4 s1a = S[(size_t)(l0+1)*128 + lane], s1b = S[(size_t)(l0+1)*128 + lane + 64];
    float4 s2a = S[(size_t)(l0+2)*128 + lane], s2b = S[(size_t)(l0+2)*128 + lane + 64];
    float4 s3a = S[(size_t)(l0+3)*128 + lane], s3b = S[(size_t)(l0+3)*128 + lane + 64];
    #pragma unroll 4
    for (int j = 0; j < 16; j++){
        int e = e0 + j;
        const float4* W = (const float4*)Win + (size_t)e * 128;
        float4 w0 = W[lane], w1 = W[lane + 64];
        float a0 = dot4(w0, s0a) + dot4(w1, s0b);
        float a1 = dot4(w0, s1a) + dot4(w1, s1b);
        float a2 = dot4(w0, s2a) + dot4(w1, s2b);
        float a3 = dot4(w0, s3a) + dot4(w1, s3b);
        float u = reduce4(a0, a1, a2, a3, lane);
        if (lane < 4) xz[(size_t)(l0 + lane) * 2048 + e] = u;
    }
}

// ---------------------------------------------------------------------------
// K3: fused conv1d+SiLU -> x_proj -> dt_proj+softplus.  One block per l (64).
// ---------------------------------------------------------------------------
__global__ __launch_bounds__(256) void mid_k(const float* __restrict__ xz,
                                             const float* __restrict__ cw,
                                             const float* __restrict__ cb,
                                             const float* __restrict__ Wx,
                                             const float* __restrict__ Wdt,
                                             const float* __restrict__ bdt,
                                             float* __restrict__ xs,
                                             float* __restrict__ xdbl,
                                             float* __restrict__ dt){
    __shared__ float xs_row[1024];
    __shared__ float xd_row[64];
    int l = blockIdx.x;
    int t = threadIdx.x;

    // conv + SiLU
    #pragma unroll
    for (int j = 0; j < 4; j++){
        int e = t + j * 256;
        float v = cb[e];
        #pragma unroll
        for (int tt = 0; tt < 4; tt++){
            int ll = l - 3 + tt;
            if (ll >= 0) v += cw[e * 4 + tt] * xz[(size_t)ll * 2048 + e];
        }
        v = v / (1.f + expf(-v));
        xs_row[e] = v;
        xs[(size_t)l * 1024 + e] = v;
    }
    __syncthreads();

    // x_proj: 64 outputs, 4 threads each
    {
        int f = t >> 2, q = t & 3;
        const float4* X  = (const float4*)xs_row;
        const float4* W4 = (const float4*)(Wx + (size_t)f * 1024);
        float acc = 0.f;
        #pragma unroll 8
        for (int k = 0; k < 64; k++){
            int idx = q * 64 + k;
            acc += dot4(X[idx], W4[idx]);
        }
        acc += __shfl_xor(acc, 1);
        acc += __shfl_xor(acc, 2);
        if (q == 0){
            xd_row[f] = acc;
            xdbl[(size_t)l * 64 + f] = acc;
        }
    }
    __syncthreads();

    // dt_proj + softplus
    #pragma unroll
    for (int j = 0; j < 4; j++){
        int e = t + j * 256;
        const float4* W4 = (const float4*)(Wdt + (size_t)e * 32);
        const float4* R  = (const float4*)xd_row;
        float acc = bdt[e];
        #pragma unroll
        for (int k4 = 0; k4 < 8; k4++) acc += dot4(R[k4], W4[k4]);
        float sp = (acc > 20.f) ? acc : log1pf(expf(acc));
        dt[(size_t)l * 1024 + e] = sp;
    }
}

// ---------------------------------------------------------------------------
// K4: selective scan + skip + gate. Thread per (e,s); 256 blocks x 64 threads
// so each CU gets one independent wave.
// ---------------------------------------------------------------------------
__global__ __launch_bounds__(64) void scan_k(const float* __restrict__ dt,
                                             const float* __restrict__ xs,
                                             const float* __restrict__ xdbl,
                                             const float* __restrict__ xz,
                                             const float* __restrict__ A_log,
                                             const float* __restrict__ Dv,
                                             float* __restrict__ y){
    int idx = blockIdx.x * 64 + threadIdx.x;   // 0..16383
    int e = idx >> 4;
    int s = idx & 15;
    float A  = -expf(A_log[e * 16 + s]);
    float Dd = Dv[e];
    float h = 0.f;
    for (int l = 0; l < 64; l++){
        float dtv = dt[l * 1024 + e];
        float xv  = xs[l * 1024 + e];
        float bv  = xdbl[l * 64 + 32 + s];
        float cv  = xdbl[l * 64 + 48 + s];
        h = expf(dtv * A) * h + (dtv * xv) * bv;
        float p = h * cv;
        p += __shfl_xor(p, 1);
        p += __shfl_xor(p, 2);
        p += __shfl_xor(p, 4);
        p += __shfl_xor(p, 8);
        if (s == 0){
            float yv = p + xv * Dd;
            float zv = xz[l * 2048 + 1024 + e];
            yv *= zv / (1.f + expf(-zv));
            y[l * 1024 + e] = yv;
        }
    }
}

// ---------------------------------------------------------------------------
// K5: out_proj  out[l,d] = dot(y[l,:1024], Wo[d,:1024])  (64 x 512)
// Wave computes 4l x 16d tile. 128 blocks x 256 threads = 512 waves.
// ---------------------------------------------------------------------------
__global__ __launch_bounds__(256) void outproj_k(const float* __restrict__ y,
                                                 const float* __restrict__ Wo,
                                                 float* __restrict__ out){
    int lane = threadIdx.x & 63;
    int wid  = blockIdx.x * 4 + (threadIdx.x >> 6);  // 0..511
    int l0 = (wid >> 5) << 2;        // 0,4,...,60
    int d0 = (wid & 31) << 4;        // 0,16,...,496
    const float4* Y = (const float4*)y;
    float4 y0[4], y1[4], y2[4], y3[4];
    #pragma unroll
    for (int q = 0; q < 4; q++){
        y0[q] = Y[(size_t)(l0+0)*256 + q*64 + lane];
        y1[q] = Y[(size_t)(l0+1)*256 + q*64 + lane];
        y2[q] = Y[(size_t)(l0+2)*256 + q*64 + lane];
        y3[q] = Y[(size_t)(l0+3)*256 + q*64 + lane];
    }
    #pragma unroll 2
    for (int j = 0; j < 16; j++){
        int d = d0 + j;
        const float4* W = (const float4*)Wo + (size_t)d * 256;
        float a0 = 0.f, a1 = 0.f, a2 = 0.f, a3 = 0.f;
        #pragma unroll
        for (int q = 0; q < 4; q++){
            float4 w = W[q * 64 + lane];
            a0 += dot4(w, y0[q]);
            a1 += dot4(w, y1[q]);
            a2 += dot4(w, y2[q]);
            a3 += dot4(w, y3[q]);
        }
        float u = reduce4(a0, a1, a2, a3, lane);
        if (lane < 4) out[(size_t)(l0 + lane) * 512 + d] = u;
    }
}

// ---------------------------------------------------------------------------
extern "C" void kernel_launch(void* const* d_in, const int* in_sizes, int n_in,
                              void* d_out, int out_size, void* d_ws, size_t ws_size,
                              hipStream_t stream){
    const float* x          = (const float*)d_in[0];
    const float* in_proj_w  = (const float*)d_in[1];
    const float* conv_w     = (const float*)d_in[2];
    const float* conv_b     = (const float*)d_in[3];
    const float* x_proj_w   = (const float*)d_in[4];
    const float* dt_proj_w  = (const float*)d_in[5];
    const float* dt_proj_b  = (const float*)d_in[6];
    const float* A_log      = (const float*)d_in[7];
    const float* Dv         = (const float*)d_in[8];
    const float* out_proj_w = (const float*)d_in[9];
    float* out = (float*)d_out;

    float* ws   = (float*)d_ws;
    float* seq  = ws;            // 64*512
    float* xz   = ws + 32768;    // 64*2048
    float* xs   = ws + 163840;   // 64*1024
    float* xdbl = ws + 229376;   // 64*64
    float* dt   = ws + 233472;   // 64*1024
    float* y    = ws + 299008;   // 64*1024

    hipLaunchKernelGGL(pool_k,    dim3(1024), dim3(256), 0, stream, x, seq);
    hipLaunchKernelGGL(inproj_k,  dim3(512),  dim3(256), 0, stream, seq, in_proj_w, xz);
    hipLaunchKernelGGL(mid_k,     dim3(64),   dim3(256), 0, stream, xz, conv_w, conv_b,
                       x_proj_w, dt_proj_w, dt_proj_b, xs, xdbl, dt);
    hipLaunchKernelGGL(scan_k,    dim3(256),  dim3(64),  0, stream, dt, xs, xdbl, xz, A_log, Dv, y);
    hipLaunchKernelGGL(outproj_k, dim3(128),  dim3(256), 0, stream, y, out_proj_w, out);
}

// Round 3
// 174.039 us; speedup vs baseline: 1.1084x; 1.1084x over previous
//
#include <hip/hip_runtime.h>
#include <math.h>

typedef float f32x4 __attribute__((ext_vector_type(4)));

__device__ __forceinline__ float dot4v(f32x4 a, f32x4 b){
    return a.x*b.x + a.y*b.y + a.z*b.z + a.w*b.w;
}
__device__ __forceinline__ float dot4(float4 a, float4 b){
    return a.x*b.x + a.y*b.y + a.z*b.z + a.w*b.w;
}

// Reduce four per-lane values across the 64-lane wave simultaneously.
// Result: lanes with (lane&3)==j hold sum of aj. 7 shuffles total.
__device__ __forceinline__ float reduce4(float a0, float a1, float a2, float a3, int lane){
    int b0 = lane & 1, b1 = lane & 2;
    float r  = b0 ? a1 : a0;
    float rt = b0 ? a0 : a1;
    r += __shfl_xor(rt, 1);
    float s  = b0 ? a3 : a2;
    float st = b0 ? a2 : a3;
    s += __shfl_xor(st, 1);
    float u  = b1 ? s : r;
    float ut = b1 ? r : s;
    u += __shfl_xor(ut, 2);
    u += __shfl_xor(u, 4);
    u += __shfl_xor(u, 8);
    u += __shfl_xor(u, 16);
    u += __shfl_xor(u, 32);
    return u;   // lane&3 selects which sum
}

// ---------------------------------------------------------------------------
// K1: AvgPool3d 16^3, 4-way split along the pooled d-window.
// wid = (c,od,oh,part): 16384 waves (32/CU resident), each reads 32 KB
// (4 d-slices x 16 rows of 512B, fully coalesced 1KB/instr), writes scaled
// partial sums to seqp[part][c*512+od*64+oh*8+ow]. Non-temporal x loads.
// ---------------------------------------------------------------------------
__global__ __launch_bounds__(256) void pool_k(const float* __restrict__ x,
                                              float* __restrict__ seqp){
    int tid  = threadIdx.x;
    int lane = tid & 63;
    int wid  = blockIdx.x * 4 + (tid >> 6);   // 0..16383
    int part = wid & 3;
    int cdh  = wid >> 2;                      // 0..4095
    int c  = cdh >> 6;
    int od = (cdh >> 3) & 7;
    int oh = cdh & 7;
    int half = lane >> 5;
    int f    = lane & 31;

    const f32x4* px = (const f32x4*)x;
    size_t base = ((size_t)(c * 128 + od * 16) * 128 + (size_t)(oh * 16 + half)) * 32 + f
                + (size_t)part * 4 * 4096;

    float acc = 0.f;
    #pragma unroll
    for (int ii = 0; ii < 4; ii++){
        size_t o = base + (size_t)ii * 4096;
        #pragma unroll
        for (int jj = 0; jj < 8; jj++){
            f32x4 v = __builtin_nontemporal_load(&px[o + (size_t)jj * 64]);
            acc += (v.x + v.y) + (v.z + v.w);
        }
    }
    acc += __shfl_xor(acc, 1);
    acc += __shfl_xor(acc, 2);
    acc += __shfl_xor(acc, 32);
    if (lane < 32 && (lane & 3) == 0){
        int ow = lane >> 2;
        seqp[part * 32768 + c * 512 + od * 64 + oh * 8 + ow] = acc * (1.0f / 4096.0f);
    }
}

// ---------------------------------------------------------------------------
// K2: in_proj  xz[l,e] = dot(seq[l,:512], Win[e,:512])   (64 x 2048)
// seq[l] = sum of 4 pool partials (summed on load, L2-resident).
// Wave computes a 4l x 16e tile. 512 blocks x 256 threads.
// ---------------------------------------------------------------------------
__device__ __forceinline__ f32x4 loadS(const f32x4* __restrict__ P, int row, int idx){
    f32x4 v = P[(size_t)row * 128 + idx];
    #pragma unroll
    for (int p = 1; p < 4; p++) v += P[(size_t)p * 8192 + (size_t)row * 128 + idx];
    return v;
}

__global__ __launch_bounds__(256) void inproj_k(const float* __restrict__ seqp,
                                                const float* __restrict__ Win,
                                                float* __restrict__ xz){
    int lane = threadIdx.x & 63;
    int wid  = blockIdx.x * 4 + (threadIdx.x >> 6);  // 0..2047
    int l0 = (wid >> 7) << 2;        // 0,4,...,60
    int e0 = (wid & 127) << 4;       // 0,16,...,2032
    const f32x4* P = (const f32x4*)seqp;
    f32x4 s0a = loadS(P, l0+0, lane), s0b = loadS(P, l0+0, lane + 64);
    f32x4 s1a = loadS(P, l0+1, lane), s1b = loadS(P, l0+1, lane + 64);
    f32x4 s2a = loadS(P, l0+2, lane), s2b = loadS(P, l0+2, lane + 64);
    f32x4 s3a = loadS(P, l0+3, lane), s3b = loadS(P, l0+3, lane + 64);
    #pragma unroll 4
    for (int j = 0; j < 16; j++){
        int e = e0 + j;
        const f32x4* W = (const f32x4*)Win + (size_t)e * 128;
        f32x4 w0 = W[lane], w1 = W[lane + 64];
        float a0 = dot4v(w0, s0a) + dot4v(w1, s0b);
        float a1 = dot4v(w0, s1a) + dot4v(w1, s1b);
        float a2 = dot4v(w0, s2a) + dot4v(w1, s2b);
        float a3 = dot4v(w0, s3a) + dot4v(w1, s3b);
        float u = reduce4(a0, a1, a2, a3, lane);
        if (lane < 4) xz[(size_t)(l0 + lane) * 2048 + e] = u;
    }
}

// ---------------------------------------------------------------------------
// K3: fused conv1d+SiLU -> x_proj -> dt_proj+softplus.  One block per l (64).
// ---------------------------------------------------------------------------
__global__ __launch_bounds__(256) void mid_k(const float* __restrict__ xz,
                                             const float* __restrict__ cw,
                                             const float* __restrict__ cb,
                                             const float* __restrict__ Wx,
                                             const float* __restrict__ Wdt,
                                             const float* __restrict__ bdt,
                                             float* __restrict__ xs,
                                             float* __restrict__ xdbl,
                                             float* __restrict__ dt){
    __shared__ float xs_row[1024];
    __shared__ float xd_row[64];
    int l = blockIdx.x;
    int t = threadIdx.x;

    // conv + SiLU
    #pragma unroll
    for (int j = 0; j < 4; j++){
        int e = t + j * 256;
        float v = cb[e];
        #pragma unroll
        for (int tt = 0; tt < 4; tt++){
            int ll = l - 3 + tt;
            if (ll >= 0) v += cw[e * 4 + tt] * xz[(size_t)ll * 2048 + e];
        }
        v = v / (1.f + expf(-v));
        xs_row[e] = v;
        xs[(size_t)l * 1024 + e] = v;
    }
    __syncthreads();

    // x_proj: 64 outputs, 4 threads each
    {
        int f = t >> 2, q = t & 3;
        const float4* X  = (const float4*)xs_row;
        const float4* W4 = (const float4*)(Wx + (size_t)f * 1024);
        float acc = 0.f;
        #pragma unroll 8
        for (int k = 0; k < 64; k++){
            int idx = q * 64 + k;
            acc += dot4(X[idx], W4[idx]);
        }
        acc += __shfl_xor(acc, 1);
        acc += __shfl_xor(acc, 2);
        if (q == 0){
            xd_row[f] = acc;
            xdbl[(size_t)l * 64 + f] = acc;
        }
    }
    __syncthreads();

    // dt_proj + softplus
    #pragma unroll
    for (int j = 0; j < 4; j++){
        int e = t + j * 256;
        const float4* W4 = (const float4*)(Wdt + (size_t)e * 32);
        const float4* R  = (const float4*)xd_row;
        float acc = bdt[e];
        #pragma unroll
        for (int k4 = 0; k4 < 8; k4++) acc += dot4(R[k4], W4[k4]);
        float sp = (acc > 20.f) ? acc : log1pf(expf(acc));
        dt[(size_t)l * 1024 + e] = sp;
    }
}

// ---------------------------------------------------------------------------
// K4: selective scan + skip + gate. Thread per (e,s); 256 blocks x 64 threads.
// ---------------------------------------------------------------------------
__global__ __launch_bounds__(64) void scan_k(const float* __restrict__ dt,
                                             const float* __restrict__ xs,
                                             const float* __restrict__ xdbl,
                                             const float* __restrict__ xz,
                                             const float* __restrict__ A_log,
                                             const float* __restrict__ Dv,
                                             float* __restrict__ y){
    int idx = blockIdx.x * 64 + threadIdx.x;   // 0..16383
    int e = idx >> 4;
    int s = idx & 15;
    float A  = -expf(A_log[e * 16 + s]);
    float Dd = Dv[e];
    float h = 0.f;
    for (int l = 0; l < 64; l++){
        float dtv = dt[l * 1024 + e];
        float xv  = xs[l * 1024 + e];
        float bv  = xdbl[l * 64 + 32 + s];
        float cv  = xdbl[l * 64 + 48 + s];
        h = expf(dtv * A) * h + (dtv * xv) * bv;
        float p = h * cv;
        p += __shfl_xor(p, 1);
        p += __shfl_xor(p, 2);
        p += __shfl_xor(p, 4);
        p += __shfl_xor(p, 8);
        if (s == 0){
            float yv = p + xv * Dd;
            float zv = xz[l * 2048 + 1024 + e];
            yv *= zv / (1.f + expf(-zv));
            y[l * 1024 + e] = yv;
        }
    }
}

// ---------------------------------------------------------------------------
// K5: out_proj  out[l,d] = dot(y[l,:1024], Wo[d,:1024])  (64 x 512)
// Wave computes 4l x 16d tile. 128 blocks x 256 threads.
// ---------------------------------------------------------------------------
__global__ __launch_bounds__(256) void outproj_k(const float* __restrict__ y,
                                                 const float* __restrict__ Wo,
                                                 float* __restrict__ out){
    int lane = threadIdx.x & 63;
    int wid  = blockIdx.x * 4 + (threadIdx.x >> 6);  // 0..511
    int l0 = (wid >> 5) << 2;        // 0,4,...,60
    int d0 = (wid & 31) << 4;        // 0,16,...,496
    const float4* Y = (const float4*)y;
    float4 y0[4], y1[4], y2[4], y3[4];
    #pragma unroll
    for (int q = 0; q < 4; q++){
        y0[q] = Y[(size_t)(l0+0)*256 + q*64 + lane];
        y1[q] = Y[(size_t)(l0+1)*256 + q*64 + lane];
        y2[q] = Y[(size_t)(l0+2)*256 + q*64 + lane];
        y3[q] = Y[(size_t)(l0+3)*256 + q*64 + lane];
    }
    #pragma unroll 2
    for (int j = 0; j < 16; j++){
        int d = d0 + j;
        const float4* W = (const float4*)Wo + (size_t)d * 256;
        float a0 = 0.f, a1 = 0.f, a2 = 0.f, a3 = 0.f;
        #pragma unroll
        for (int q = 0; q < 4; q++){
            float4 w = W[q * 64 + lane];
            a0 += dot4(w, y0[q]);
            a1 += dot4(w, y1[q]);
            a2 += dot4(w, y2[q]);
            a3 += dot4(w, y3[q]);
        }
        float u = reduce4(a0, a1, a2, a3, lane);
        if (lane < 4) out[(size_t)(l0 + lane) * 512 + d] = u;
    }
}

// ---------------------------------------------------------------------------
extern "C" void kernel_launch(void* const* d_in, const int* in_sizes, int n_in,
                              void* d_out, int out_size, void* d_ws, size_t ws_size,
                              hipStream_t stream){
    const float* x          = (const float*)d_in[0];
    const float* in_proj_w  = (const float*)d_in[1];
    const float* conv_w     = (const float*)d_in[2];
    const float* conv_b     = (const float*)d_in[3];
    const float* x_proj_w   = (const float*)d_in[4];
    const float* dt_proj_w  = (const float*)d_in[5];
    const float* dt_proj_b  = (const float*)d_in[6];
    const float* A_log      = (const float*)d_in[7];
    const float* Dv         = (const float*)d_in[8];
    const float* out_proj_w = (const float*)d_in[9];
    float* out = (float*)d_out;

    float* ws   = (float*)d_ws;
    float* seqp = ws;            // 4 * 32768 = 131072
    float* xz   = ws + 131072;   // 64*2048   = 131072
    float* xs   = ws + 262144;   // 64*1024   = 65536
    float* xdbl = ws + 327680;   // 64*64     = 4096
    float* dt   = ws + 331776;   // 64*1024   = 65536
    float* y    = ws + 397312;   // 64*1024   = 65536

    hipLaunchKernelGGL(pool_k,    dim3(4096), dim3(256), 0, stream, x, seqp);
    hipLaunchKernelGGL(inproj_k,  dim3(512),  dim3(256), 0, stream, seqp, in_proj_w, xz);
    hipLaunchKernelGGL(mid_k,     dim3(64),   dim3(256), 0, stream, xz, conv_w, conv_b,
                       x_proj_w, dt_proj_w, dt_proj_b, xs, xdbl, dt);
    hipLaunchKernelGGL(scan_k,    dim3(256),  dim3(64),  0, stream, dt, xs, xdbl, xz, A_log, Dv, y);
    hipLaunchKernelGGL(outproj_k, dim3(128),  dim3(256), 0, stream, y, out_proj_w, out);
}

// Round 4
// 134.714 us; speedup vs baseline: 1.4320x; 1.2919x over previous
//
#include <hip/hip_runtime.h>
#include <math.h>

typedef float f32x4 __attribute__((ext_vector_type(4)));

__device__ __forceinline__ float dot4v(f32x4 a, f32x4 b){
    return a.x*b.x + a.y*b.y + a.z*b.z + a.w*b.w;
}
__device__ __forceinline__ float dot4(float4 a, float4 b){
    return a.x*b.x + a.y*b.y + a.z*b.z + a.w*b.w;
}

// Reduce four per-lane values across the 64-lane wave simultaneously.
// Result: lanes with (lane&3)==j hold sum of aj. 7 shuffles total.
__device__ __forceinline__ float reduce4(float a0, float a1, float a2, float a3, int lane){
    int b0 = lane & 1, b1 = lane & 2;
    float r  = b0 ? a1 : a0;
    float rt = b0 ? a0 : a1;
    r += __shfl_xor(rt, 1);
    float s  = b0 ? a3 : a2;
    float st = b0 ? a2 : a3;
    s += __shfl_xor(st, 1);
    float u  = b1 ? s : r;
    float ut = b1 ? r : s;
    u += __shfl_xor(ut, 2);
    u += __shfl_xor(u, 4);
    u += __shfl_xor(u, 8);
    u += __shfl_xor(u, 16);
    u += __shfl_xor(u, 32);
    return u;   // lane&3 selects which sum
}

// ---------------------------------------------------------------------------
// K1: AvgPool3d 16^3, 4-way split along the pooled d-window. (unchanged R3)
// ---------------------------------------------------------------------------
__global__ __launch_bounds__(256) void pool_k(const float* __restrict__ x,
                                              float* __restrict__ seqp){
    int tid  = threadIdx.x;
    int lane = tid & 63;
    int wid  = blockIdx.x * 4 + (tid >> 6);   // 0..16383
    int part = wid & 3;
    int cdh  = wid >> 2;                      // 0..4095
    int c  = cdh >> 6;
    int od = (cdh >> 3) & 7;
    int oh = cdh & 7;
    int half = lane >> 5;
    int f    = lane & 31;

    const f32x4* px = (const f32x4*)x;
    size_t base = ((size_t)(c * 128 + od * 16) * 128 + (size_t)(oh * 16 + half)) * 32 + f
                + (size_t)part * 4 * 4096;

    float acc = 0.f;
    #pragma unroll
    for (int ii = 0; ii < 4; ii++){
        size_t o = base + (size_t)ii * 4096;
        #pragma unroll
        for (int jj = 0; jj < 8; jj++){
            f32x4 v = __builtin_nontemporal_load(&px[o + (size_t)jj * 64]);
            acc += (v.x + v.y) + (v.z + v.w);
        }
    }
    acc += __shfl_xor(acc, 1);
    acc += __shfl_xor(acc, 2);
    acc += __shfl_xor(acc, 32);
    if (lane < 32 && (lane & 3) == 0){
        int ow = lane >> 2;
        seqp[part * 32768 + c * 512 + od * 64 + oh * 8 + ow] = acc * (1.0f / 4096.0f);
    }
}

// ---------------------------------------------------------------------------
// K2: in_proj (unchanged R3): xz[l,e] = dot(seq[l,:512], Win[e,:512])
// ---------------------------------------------------------------------------
__device__ __forceinline__ f32x4 loadS(const f32x4* __restrict__ P, int row, int idx){
    f32x4 v = P[(size_t)row * 128 + idx];
    #pragma unroll
    for (int p = 1; p < 4; p++) v += P[(size_t)p * 8192 + (size_t)row * 128 + idx];
    return v;
}

__global__ __launch_bounds__(256) void inproj_k(const float* __restrict__ seqp,
                                                const float* __restrict__ Win,
                                                float* __restrict__ xz){
    int lane = threadIdx.x & 63;
    int wid  = blockIdx.x * 4 + (threadIdx.x >> 6);  // 0..2047
    int l0 = (wid >> 7) << 2;
    int e0 = (wid & 127) << 4;
    const f32x4* P = (const f32x4*)seqp;
    f32x4 s0a = loadS(P, l0+0, lane), s0b = loadS(P, l0+0, lane + 64);
    f32x4 s1a = loadS(P, l0+1, lane), s1b = loadS(P, l0+1, lane + 64);
    f32x4 s2a = loadS(P, l0+2, lane), s2b = loadS(P, l0+2, lane + 64);
    f32x4 s3a = loadS(P, l0+3, lane), s3b = loadS(P, l0+3, lane + 64);
    #pragma unroll 4
    for (int j = 0; j < 16; j++){
        int e = e0 + j;
        const f32x4* W = (const f32x4*)Win + (size_t)e * 128;
        f32x4 w0 = W[lane], w1 = W[lane + 64];
        float a0 = dot4v(w0, s0a) + dot4v(w1, s0b);
        float a1 = dot4v(w0, s1a) + dot4v(w1, s1b);
        float a2 = dot4v(w0, s2a) + dot4v(w1, s2b);
        float a3 = dot4v(w0, s3a) + dot4v(w1, s3b);
        float u = reduce4(a0, a1, a2, a3, lane);
        if (lane < 4) xz[(size_t)(l0 + lane) * 2048 + e] = u;
    }
}

// ---------------------------------------------------------------------------
// K3: fused conv1d+SiLU -> x_proj -> dt_proj+softplus. One block per l (64).
// Emits TRANSPOSED (e-major / s-major) tensors for the scan:
//   xsT[e][l], zsT[e][l] = silu(z), dtT[e][l] = softplus(...), bcT[s][l] (B then C)
// ---------------------------------------------------------------------------
__global__ __launch_bounds__(256) void mid_k(const float* __restrict__ xz,
                                             const float* __restrict__ cw,
                                             const float* __restrict__ cb,
                                             const float* __restrict__ Wx,
                                             const float* __restrict__ Wdt,
                                             const float* __restrict__ bdt,
                                             float* __restrict__ xsT,
                                             float* __restrict__ zsT,
                                             float* __restrict__ dtT,
                                             float* __restrict__ bcT){
    __shared__ float xs_row[1024];
    __shared__ float xd_row[64];
    int l = blockIdx.x;
    int t = threadIdx.x;

    // conv + SiLU (+ gate precompute)
    #pragma unroll
    for (int j = 0; j < 4; j++){
        int e = t + j * 256;
        float v = cb[e];
        #pragma unroll
        for (int tt = 0; tt < 4; tt++){
            int ll = l - 3 + tt;
            if (ll >= 0) v += cw[e * 4 + tt] * xz[(size_t)ll * 2048 + e];
        }
        v = v / (1.f + expf(-v));
        xs_row[e] = v;
        xsT[(size_t)e * 64 + l] = v;
        float zv = xz[(size_t)l * 2048 + 1024 + e];
        zsT[(size_t)e * 64 + l] = zv / (1.f + expf(-zv));
    }
    __syncthreads();

    // x_proj: 64 outputs, 4 threads each
    {
        int f = t >> 2, q = t & 3;
        const float4* X  = (const float4*)xs_row;
        const float4* W4 = (const float4*)(Wx + (size_t)f * 1024);
        float acc = 0.f;
        #pragma unroll 8
        for (int k = 0; k < 64; k++){
            int idx = q * 64 + k;
            acc += dot4(X[idx], W4[idx]);
        }
        acc += __shfl_xor(acc, 1);
        acc += __shfl_xor(acc, 2);
        if (q == 0){
            xd_row[f] = acc;
            if (f >= 32) bcT[(size_t)(f - 32) * 64 + l] = acc;  // B: 0..15, C: 16..31
        }
    }
    __syncthreads();

    // dt_proj + softplus  (uses first 32 entries of xd_row)
    #pragma unroll
    for (int j = 0; j < 4; j++){
        int e = t + j * 256;
        const float4* W4 = (const float4*)(Wdt + (size_t)e * 32);
        const float4* R  = (const float4*)xd_row;
        float acc = bdt[e];
        #pragma unroll
        for (int k4 = 0; k4 < 8; k4++) acc += dot4(R[k4], W4[k4]);
        float sp = (acc > 20.f) ? acc : log1pf(expf(acc));
        dtT[(size_t)e * 64 + l] = sp;
    }
}

// ---------------------------------------------------------------------------
// K4: parallel selective scan. Block per e (1024 blocks x 256 threads).
// lane = timestep l; Hillis-Steele inclusive scan on (a,b) pairs (6 shuffle
// steps) replaces the 64-step serial recurrence. Wave w handles s = 4w..4w+3;
// LDS reduce over the 4 waves; fused skip (D) and silu(z) gate.
// ---------------------------------------------------------------------------
__global__ __launch_bounds__(256) void scan_k(const float* __restrict__ dtT,
                                              const float* __restrict__ xsT,
                                              const float* __restrict__ zsT,
                                              const float* __restrict__ bcT,
                                              const float* __restrict__ A_log,
                                              const float* __restrict__ Dv,
                                              float* __restrict__ y){
    __shared__ float red[4][64];
    int e    = blockIdx.x;           // 0..1023
    int lane = threadIdx.x & 63;     // = l
    int w    = threadIdx.x >> 6;     // 0..3

    float dtv = dtT[(size_t)e * 64 + lane];
    float xv  = xsT[(size_t)e * 64 + lane];

    float py = 0.f;
    #pragma unroll
    for (int i = 0; i < 4; i++){
        int s = w * 4 + i;
        float A = -expf(A_log[e * 16 + s]);
        float a = expf(dtv * A);
        float b = (dtv * xv) * bcT[s * 64 + lane];
        #pragma unroll
        for (int d = 1; d < 64; d <<= 1){
            float ap = __shfl_up(a, d);
            float bp = __shfl_up(b, d);
            if (lane >= d){ b += a * bp; a *= ap; }
        }
        py += b * bcT[(16 + s) * 64 + lane];
    }
    red[w][lane] = py;
    __syncthreads();
    if (threadIdx.x < 64){
        float tot = red[0][lane] + red[1][lane] + red[2][lane] + red[3][lane];
        float yv = (tot + xv * Dv[e]) * zsT[(size_t)e * 64 + lane];
        y[(size_t)lane * 1024 + e] = yv;
    }
}

// ---------------------------------------------------------------------------
// K5: out_proj (unchanged R3): out[l,d] = dot(y[l,:1024], Wo[d,:1024])
// ---------------------------------------------------------------------------
__global__ __launch_bounds__(256) void outproj_k(const float* __restrict__ y,
                                                 const float* __restrict__ Wo,
                                                 float* __restrict__ out){
    int lane = threadIdx.x & 63;
    int wid  = blockIdx.x * 4 + (threadIdx.x >> 6);  // 0..511
    int l0 = (wid >> 5) << 2;
    int d0 = (wid & 31) << 4;
    const float4* Y = (const float4*)y;
    float4 y0[4], y1[4], y2[4], y3[4];
    #pragma unroll
    for (int q = 0; q < 4; q++){
        y0[q] = Y[(size_t)(l0+0)*256 + q*64 + lane];
        y1[q] = Y[(size_t)(l0+1)*256 + q*64 + lane];
        y2[q] = Y[(size_t)(l0+2)*256 + q*64 + lane];
        y3[q] = Y[(size_t)(l0+3)*256 + q*64 + lane];
    }
    #pragma unroll 2
    for (int j = 0; j < 16; j++){
        int d = d0 + j;
        const float4* W = (const float4*)Wo + (size_t)d * 256;
        float a0 = 0.f, a1 = 0.f, a2 = 0.f, a3 = 0.f;
        #pragma unroll
        for (int q = 0; q < 4; q++){
            float4 w = W[q * 64 + lane];
            a0 += dot4(w, y0[q]);
            a1 += dot4(w, y1[q]);
            a2 += dot4(w, y2[q]);
            a3 += dot4(w, y3[q]);
        }
        float u = reduce4(a0, a1, a2, a3, lane);
        if (lane < 4) out[(size_t)(l0 + lane) * 512 + d] = u;
    }
}

// ---------------------------------------------------------------------------
extern "C" void kernel_launch(void* const* d_in, const int* in_sizes, int n_in,
                              void* d_out, int out_size, void* d_ws, size_t ws_size,
                              hipStream_t stream){
    const float* x          = (const float*)d_in[0];
    const float* in_proj_w  = (const float*)d_in[1];
    const float* conv_w     = (const float*)d_in[2];
    const float* conv_b     = (const float*)d_in[3];
    const float* x_proj_w   = (const float*)d_in[4];
    const float* dt_proj_w  = (const float*)d_in[5];
    const float* dt_proj_b  = (const float*)d_in[6];
    const float* A_log      = (const float*)d_in[7];
    const float* Dv         = (const float*)d_in[8];
    const float* out_proj_w = (const float*)d_in[9];
    float* out = (float*)d_out;

    float* ws   = (float*)d_ws;
    float* seqp = ws;            // 4*32768  = 131072
    float* xz   = ws + 131072;   // 64*2048  = 131072
    float* xsT  = ws + 262144;   // 1024*64  = 65536
    float* zsT  = ws + 327680;   // 1024*64  = 65536
    float* dtT  = ws + 393216;   // 1024*64  = 65536
    float* bcT  = ws + 458752;   // 32*64    = 2048
    float* y    = ws + 460800;   // 64*1024  = 65536

    hipLaunchKernelGGL(pool_k,    dim3(4096), dim3(256), 0, stream, x, seqp);
    hipLaunchKernelGGL(inproj_k,  dim3(512),  dim3(256), 0, stream, seqp, in_proj_w, xz);
    hipLaunchKernelGGL(mid_k,     dim3(64),   dim3(256), 0, stream, xz, conv_w, conv_b,
                       x_proj_w, dt_proj_w, dt_proj_b, xsT, zsT, dtT, bcT);
    hipLaunchKernelGGL(scan_k,    dim3(1024), dim3(256), 0, stream, dtT, xsT, zsT, bcT, A_log, Dv, y);
    hipLaunchKernelGGL(outproj_k, dim3(128),  dim3(256), 0, stream, y, out_proj_w, out);
}

// Round 5
// 126.842 us; speedup vs baseline: 1.5209x; 1.0621x over previous
//
#include <hip/hip_runtime.h>
#include <math.h>

typedef float f32x4 __attribute__((ext_vector_type(4)));

__device__ __forceinline__ float dot4v(f32x4 a, f32x4 b){
    return a.x*b.x + a.y*b.y + a.z*b.z + a.w*b.w;
}
__device__ __forceinline__ float dot4(float4 a, float4 b){
    return a.x*b.x + a.y*b.y + a.z*b.z + a.w*b.w;
}

// Reduce four per-lane values across the 64-lane wave simultaneously.
// Result: lanes with (lane&3)==j hold sum of aj. 7 shuffles total.
__device__ __forceinline__ float reduce4(float a0, float a1, float a2, float a3, int lane){
    int b0 = lane & 1, b1 = lane & 2;
    float r  = b0 ? a1 : a0;
    float rt = b0 ? a0 : a1;
    r += __shfl_xor(rt, 1);
    float s  = b0 ? a3 : a2;
    float st = b0 ? a2 : a3;
    s += __shfl_xor(st, 1);
    float u  = b1 ? s : r;
    float ut = b1 ? r : s;
    u += __shfl_xor(ut, 2);
    u += __shfl_xor(u, 4);
    u += __shfl_xor(u, 8);
    u += __shfl_xor(u, 16);
    u += __shfl_xor(u, 32);
    return u;   // lane&3 selects which sum
}

// ---------------------------------------------------------------------------
// K1: AvgPool3d 16^3. Block per (c,od,oh); wave = d-window quarter.
// Same fully-coalesced 1KB-load pattern as R4, but the 4 partials are
// LDS-reduced in-block -> seq is FINAL (no partial re-read downstream).
// ---------------------------------------------------------------------------
__global__ __launch_bounds__(256) void pool_k(const float* __restrict__ x,
                                              float* __restrict__ seq){
    __shared__ float red[4][8];
    int tid  = threadIdx.x;
    int lane = tid & 63;
    int part = tid >> 6;                      // 0..3
    int cdh  = blockIdx.x;                    // 0..4095
    int c  = cdh >> 6;
    int od = (cdh >> 3) & 7;
    int oh = cdh & 7;
    int half = lane >> 5;
    int f    = lane & 31;

    const f32x4* px = (const f32x4*)x;
    size_t base = ((size_t)(c * 128 + od * 16) * 128 + (size_t)(oh * 16 + half)) * 32 + f
                + (size_t)part * 4 * 4096;

    float acc = 0.f;
    #pragma unroll
    for (int ii = 0; ii < 4; ii++){
        size_t o = base + (size_t)ii * 4096;
        #pragma unroll
        for (int jj = 0; jj < 8; jj++){
            f32x4 v = __builtin_nontemporal_load(&px[o + (size_t)jj * 64]);
            acc += (v.x + v.y) + (v.z + v.w);
        }
    }
    acc += __shfl_xor(acc, 1);
    acc += __shfl_xor(acc, 2);
    acc += __shfl_xor(acc, 32);
    if (lane < 32 && (lane & 3) == 0) red[part][lane >> 2] = acc;
    __syncthreads();
    if (tid < 8){
        float v = red[0][tid] + red[1][tid] + red[2][tid] + red[3][tid];
        seq[c * 512 + od * 64 + oh * 8 + tid] = v * (1.0f / 4096.0f);
    }
}

// ---------------------------------------------------------------------------
// K2: in_proj  xz[l,e] = dot(seq[l,:512], Win[e,:512])   (64 x 2048)
// Wave computes 8l x 16e: seq rows in regs (16 f32x4), each Win row loaded
// once per wave -> 32 MB total W traffic (was 64). 256 blocks x 256 thr.
// ---------------------------------------------------------------------------
__global__ __launch_bounds__(256) void inproj_k(const float* __restrict__ seq,
                                                const float* __restrict__ Win,
                                                float* __restrict__ xz){
    int lane = threadIdx.x & 63;
    int wid  = blockIdx.x * 4 + (threadIdx.x >> 6);  // 0..1023
    int l0 = (wid >> 7) << 3;        // 8 groups of 8 l
    int e0 = (wid & 127) << 4;       // 128 groups of 16 e
    const f32x4* S = (const f32x4*)seq;
    f32x4 sa[8], sb[8];
    #pragma unroll
    for (int r = 0; r < 8; r++){
        sa[r] = S[(size_t)(l0 + r) * 128 + lane];
        sb[r] = S[(size_t)(l0 + r) * 128 + lane + 64];
    }
    #pragma unroll 2
    for (int j = 0; j < 16; j++){
        int e = e0 + j;
        const f32x4* W = (const f32x4*)Win + (size_t)e * 128;
        f32x4 w0 = W[lane], w1 = W[lane + 64];
        float a[8];
        #pragma unroll
        for (int r = 0; r < 8; r++) a[r] = dot4v(w0, sa[r]) + dot4v(w1, sb[r]);
        float u0 = reduce4(a[0], a[1], a[2], a[3], lane);
        float u1 = reduce4(a[4], a[5], a[6], a[7], lane);
        if (lane < 4){
            xz[(size_t)(l0 + lane) * 2048 + e]     = u0;
            xz[(size_t)(l0 + 4 + lane) * 2048 + e] = u1;
        }
    }
}

// ---------------------------------------------------------------------------
// K3: fused conv1d+SiLU + gate + x_proj. One block per l, 1024 threads.
// conv: thread = e (1 elem). x_proj: 16 threads per output f (16 serial
// iters), 4-step shuffle reduce. Emits xsT/zsT (e-major), bcT[s][l],
// xdT[k][l] (dt_proj folded into scan_k).
// ---------------------------------------------------------------------------
__global__ __launch_bounds__(1024) void cxp_k(const float* __restrict__ xz,
                                              const float* __restrict__ cw,
                                              const float* __restrict__ cb,
                                              const float* __restrict__ Wx,
                                              float* __restrict__ xsT,
                                              float* __restrict__ zsT,
                                              float* __restrict__ bcT,
                                              float* __restrict__ xdT){
    __shared__ float xs_row[1024];
    int l = blockIdx.x;
    int t = threadIdx.x;   // = e for conv phase

    {
        int e = t;
        float v = cb[e];
        #pragma unroll
        for (int tt = 0; tt < 4; tt++){
            int ll = l - 3 + tt;
            if (ll >= 0) v += cw[e * 4 + tt] * xz[(size_t)ll * 2048 + e];
        }
        v = v / (1.f + expf(-v));
        xs_row[e] = v;
        xsT[(size_t)e * 64 + l] = v;
        float zv = xz[(size_t)l * 2048 + 1024 + e];
        zsT[(size_t)e * 64 + l] = zv / (1.f + expf(-zv));
    }
    __syncthreads();

    // x_proj: f = t>>4 (0..63), q = t&15 covers k-slice of 64 floats
    {
        int f = t >> 4, q = t & 15;
        const float4* X  = (const float4*)xs_row;
        const float4* W4 = (const float4*)(Wx + (size_t)f * 1024);
        float acc = 0.f;
        #pragma unroll
        for (int k4 = 0; k4 < 16; k4++){
            int idx = q * 16 + k4;
            acc += dot4(X[idx], W4[idx]);
        }
        acc += __shfl_xor(acc, 1);
        acc += __shfl_xor(acc, 2);
        acc += __shfl_xor(acc, 4);
        acc += __shfl_xor(acc, 8);
        if (q == 0){
            if (f < 32) xdT[(size_t)f * 64 + l] = acc;          // dt-rank part
            else        bcT[(size_t)(f - 32) * 64 + l] = acc;   // B: 0..15, C: 16..31
        }
    }
}

// ---------------------------------------------------------------------------
// K4: fused dt_proj+softplus + parallel selective scan + skip + gate.
// Block per e (1024 blocks x 256 thr). lane = timestep l. Each wave
// recomputes dt (coalesced xdT reads, uniform Wdt scalar loads), then
// Hillis-Steele scan per s (6 shuffle steps), LDS reduce over 4 waves.
// ---------------------------------------------------------------------------
__global__ __launch_bounds__(256) void scan_k(const float* __restrict__ xdT,
                                              const float* __restrict__ bcT,
                                              const float* __restrict__ xsT,
                                              const float* __restrict__ zsT,
                                              const float* __restrict__ Wdt,
                                              const float* __restrict__ bdt,
                                              const float* __restrict__ A_log,
                                              const float* __restrict__ Dv,
                                              float* __restrict__ y){
    __shared__ float red[4][64];
    int e    = blockIdx.x;           // 0..1023
    int lane = threadIdx.x & 63;     // = l
    int w    = threadIdx.x >> 6;     // 0..3

    // dt_proj + softplus (redundant per wave; coalesced)
    float acc = bdt[e];
    #pragma unroll 8
    for (int k = 0; k < 32; k++) acc += xdT[k * 64 + lane] * Wdt[e * 32 + k];
    float dtv = (acc > 20.f) ? acc : log1pf(expf(acc));
    float xv  = xsT[(size_t)e * 64 + lane];

    float py = 0.f;
    #pragma unroll
    for (int i = 0; i < 4; i++){
        int s = w * 4 + i;
        float A = -expf(A_log[e * 16 + s]);
        float a = expf(dtv * A);
        float b = (dtv * xv) * bcT[s * 64 + lane];
        #pragma unroll
        for (int d = 1; d < 64; d <<= 1){
            float ap = __shfl_up(a, d);
            float bp = __shfl_up(b, d);
            if (lane >= d){ b += a * bp; a *= ap; }
        }
        py += b * bcT[(16 + s) * 64 + lane];
    }
    red[w][lane] = py;
    __syncthreads();
    if (threadIdx.x < 64){
        float tot = red[0][lane] + red[1][lane] + red[2][lane] + red[3][lane];
        float yv = (tot + xv * Dv[e]) * zsT[(size_t)e * 64 + lane];
        y[(size_t)lane * 1024 + e] = yv;
    }
}

// ---------------------------------------------------------------------------
// K5: out_proj  out[l,d] = dot(y[l,:1024], Wo[d,:1024])  (64 x 512)
// Wave computes 4l x 16d tile. 128 blocks x 256 threads.
// ---------------------------------------------------------------------------
__global__ __launch_bounds__(256) void outproj_k(const float* __restrict__ y,
                                                 const float* __restrict__ Wo,
                                                 float* __restrict__ out){
    int lane = threadIdx.x & 63;
    int wid  = blockIdx.x * 4 + (threadIdx.x >> 6);  // 0..511
    int l0 = (wid >> 5) << 2;
    int d0 = (wid & 31) << 4;
    const float4* Y = (const float4*)y;
    float4 y0[4], y1[4], y2[4], y3[4];
    #pragma unroll
    for (int q = 0; q < 4; q++){
        y0[q] = Y[(size_t)(l0+0)*256 + q*64 + lane];
        y1[q] = Y[(size_t)(l0+1)*256 + q*64 + lane];
        y2[q] = Y[(size_t)(l0+2)*256 + q*64 + lane];
        y3[q] = Y[(size_t)(l0+3)*256 + q*64 + lane];
    }
    #pragma unroll 2
    for (int j = 0; j < 16; j++){
        int d = d0 + j;
        const float4* W = (const float4*)Wo + (size_t)d * 256;
        float a0 = 0.f, a1 = 0.f, a2 = 0.f, a3 = 0.f;
        #pragma unroll
        for (int q = 0; q < 4; q++){
            float4 w = W[q * 64 + lane];
            a0 += dot4(w, y0[q]);
            a1 += dot4(w, y1[q]);
            a2 += dot4(w, y2[q]);
            a3 += dot4(w, y3[q]);
        }
        float u = reduce4(a0, a1, a2, a3, lane);
        if (lane < 4) out[(size_t)(l0 + lane) * 512 + d] = u;
    }
}

// ---------------------------------------------------------------------------
extern "C" void kernel_launch(void* const* d_in, const int* in_sizes, int n_in,
                              void* d_out, int out_size, void* d_ws, size_t ws_size,
                              hipStream_t stream){
    const float* x          = (const float*)d_in[0];
    const float* in_proj_w  = (const float*)d_in[1];
    const float* conv_w     = (const float*)d_in[2];
    const float* conv_b     = (const float*)d_in[3];
    const float* x_proj_w   = (const float*)d_in[4];
    const float* dt_proj_w  = (const float*)d_in[5];
    const float* dt_proj_b  = (const float*)d_in[6];
    const float* A_log      = (const float*)d_in[7];
    const float* Dv         = (const float*)d_in[8];
    const float* out_proj_w = (const float*)d_in[9];
    float* out = (float*)d_out;

    float* ws   = (float*)d_ws;
    float* seq  = ws;            // 64*512   = 32768
    float* xz   = ws + 32768;    // 64*2048  = 131072
    float* xsT  = ws + 163840;   // 1024*64  = 65536
    float* zsT  = ws + 229376;   // 1024*64  = 65536
    float* bcT  = ws + 294912;   // 32*64    = 2048
    float* xdT  = ws + 296960;   // 32*64    = 2048
    float* y    = ws + 299008;   // 64*1024  = 65536

    hipLaunchKernelGGL(pool_k,    dim3(4096), dim3(256),  0, stream, x, seq);
    hipLaunchKernelGGL(inproj_k,  dim3(256),  dim3(256),  0, stream, seq, in_proj_w, xz);
    hipLaunchKernelGGL(cxp_k,     dim3(64),   dim3(1024), 0, stream, xz, conv_w, conv_b,
                       x_proj_w, xsT, zsT, bcT, xdT);
    hipLaunchKernelGGL(scan_k,    dim3(1024), dim3(256),  0, stream, xdT, bcT, xsT, zsT,
                       dt_proj_w, dt_proj_b, A_log, Dv, y);
    hipLaunchKernelGGL(outproj_k, dim3(128),  dim3(256),  0, stream, y, out_proj_w, out);
}